// Round 7
// baseline (1153.404 us; speedup 1.0000x reference)
//
#include <hip/hip_runtime.h>
#include <hip/hip_cooperative_groups.h>

namespace cg = cooperative_groups;

#define NQ 19
#define SZ (1u << NQ)

struct Params {
    const int* ei;
    const float* state; const float* mass; const float* spin; const float* charge;
    const float* p_norm; const float* theta;
    const float* gnw; const float* gnb; const float* gew; const float* geb;
    const float* nw; const float* nb; const float* ew; const float* eb;
    const float* qw;
    float2* buf0; float2* buf1;
    double* partial;
    float* out;
};

// Ring permutation inverse (bit space):
//   b = (c ^ (c>>1)) & 0x1FFFF ; b17 = c0^c17^c18 ; b18 = c0^c18
// Bits >=11 of pinv(c) depend ONLY on c0 and c bits 11..18.
__device__ __forceinline__ unsigned pinv(unsigned c)
{
    unsigned y = (c ^ (c >> 1)) & 0x1FFFFu;
    unsigned c0 = c & 1u, c17 = (c >> 17) & 1u, c18 = (c >> 18) & 1u;
    return y | ((c0 ^ c17 ^ c18) << 17) | ((c0 ^ c18) << 18);
}

// Padded LDS index: +2 float2 per 8 (keeps 8-groups intact; float4-safe).
__device__ __forceinline__ unsigned padl(unsigned l) { return l + 2u * (l >> 3); }

__device__ __forceinline__ void bfly(float2& a, float2& b,
                                     float2 u00, float2 u01,
                                     float2 u10, float2 u11)
{
    float2 na, nb;
    na.x = u00.x * a.x - u00.y * a.y + u01.x * b.x - u01.y * b.y;
    na.y = u00.x * a.y + u00.y * a.x + u01.x * b.y + u01.y * b.x;
    nb.x = u10.x * a.x - u10.y * a.y + u11.x * b.x - u11.y * b.y;
    nb.y = u10.x * a.y + u10.y * a.x + u11.x * b.y + u11.y * b.x;
    a = na;
    b = nb;
}

// Apply n gates on amp bits ampbit0.., mapped to register-index bits jbit0..
__device__ __forceinline__ void apply_gates(float2 r[4], const float2* Gl,
                                            int ampbit0, int jbit0, int n)
{
    #pragma unroll
    for (int k = 0; k < n; ++k) {
        const float2 u00 = Gl[(ampbit0 + k) * 4 + 0];
        const float2 u01 = Gl[(ampbit0 + k) * 4 + 1];
        const float2 u10 = Gl[(ampbit0 + k) * 4 + 2];
        const float2 u11 = Gl[(ampbit0 + k) * 4 + 3];
        const int m = 1 << (jbit0 + k);
        #pragma unroll
        for (int j = 0; j < 4; ++j)
            if (!(j & m)) bfly(r[j], r[j | m], u00, u01, u10, u11);
    }
}

// Pass-A tail: gates on c bits 0..10 through the 6 register layouts
// (round-5-verified index math).
__device__ __forceinline__ void passA_tail(float2 r[4], const float2* Gl,
                                           unsigned t, float2* X0, float2* X1)
{
    apply_gates(r, Gl, 0, 0, 2);
    // P0 -> P1 (X0)
    *reinterpret_cast<float4*>(&X0[padl(t << 2)]) =
        make_float4(r[0].x, r[0].y, r[1].x, r[1].y);
    *reinterpret_cast<float4*>(&X0[padl((t << 2) + 2u)]) =
        make_float4(r[2].x, r[2].y, r[3].x, r[3].y);
    __syncthreads();
    #pragma unroll
    for (int j = 0; j < 4; ++j)
        r[j] = X0[padl((t & 3u) | ((unsigned)j << 2) | ((t >> 2) << 4))];
    apply_gates(r, Gl, 2, 0, 2);
    // P1 -> P2 (X1)
    #pragma unroll
    for (int j = 0; j < 4; ++j)
        X1[padl((t & 3u) | ((unsigned)j << 2) | ((t >> 2) << 4))] = r[j];
    __syncthreads();
    #pragma unroll
    for (int j = 0; j < 4; ++j)
        r[j] = X1[padl((t & 15u) | ((unsigned)j << 4) | ((t >> 4) << 6))];
    apply_gates(r, Gl, 4, 0, 2);
    // P2 -> P3 (X0)
    #pragma unroll
    for (int j = 0; j < 4; ++j)
        X0[padl((t & 15u) | ((unsigned)j << 4) | ((t >> 4) << 6))] = r[j];
    __syncthreads();
    #pragma unroll
    for (int j = 0; j < 4; ++j)
        r[j] = X0[padl((t & 63u) | ((unsigned)j << 6) | ((t >> 6) << 8))];
    apply_gates(r, Gl, 6, 0, 2);
    // P3 -> P4 (X1)
    #pragma unroll
    for (int j = 0; j < 4; ++j)
        X1[padl((t & 63u) | ((unsigned)j << 6) | ((t >> 6) << 8))] = r[j];
    __syncthreads();
    #pragma unroll
    for (int j = 0; j < 4; ++j)
        r[j] = X1[padl((t & 255u) | ((unsigned)j << 8) | ((t >> 8) << 10))];
    apply_gates(r, Gl, 8, 0, 2);
    // P4 -> P5 (X0)
    #pragma unroll
    for (int j = 0; j < 4; ++j)
        X0[padl((t & 255u) | ((unsigned)j << 8) | ((t >> 8) << 10))] = r[j];
    __syncthreads();
    #pragma unroll
    for (int j = 0; j < 4; ++j)
        r[j] = X0[padl(t | ((unsigned)j << 9))];
    apply_gates(r, Gl, 10, 1, 1);          // gate c10 = l10 = j bit1
}

// Pass-B gates on c bits 11..18 (tile l: l0..l2=c0..c2, l3..l10=c11..c18).
__device__ __forceinline__ void passB_gates(float2 r[4], const float2* Gl,
                                            unsigned t, float2* X0, float2* X1)
{
    apply_gates(r, Gl, 11, 0, 2);
    // M0 -> M1 (X0)
    #pragma unroll
    for (int j = 0; j < 4; ++j)
        X0[padl((t & 7u) | ((unsigned)j << 3) | ((t >> 3) << 5))] = r[j];
    __syncthreads();
    #pragma unroll
    for (int j = 0; j < 4; ++j)
        r[j] = X0[padl((t & 31u) | ((unsigned)j << 5) | ((t >> 5) << 7))];
    apply_gates(r, Gl, 13, 0, 2);
    // M1 -> M2 (X1)
    #pragma unroll
    for (int j = 0; j < 4; ++j)
        X1[padl((t & 31u) | ((unsigned)j << 5) | ((t >> 5) << 7))] = r[j];
    __syncthreads();
    #pragma unroll
    for (int j = 0; j < 4; ++j)
        r[j] = X1[padl((t & 127u) | ((unsigned)j << 7) | ((t >> 7) << 9))];
    apply_gates(r, Gl, 15, 0, 2);
    // M2 -> M3 (X0)
    #pragma unroll
    for (int j = 0; j < 4; ++j)
        X0[padl((t & 127u) | ((unsigned)j << 7) | ((t >> 7) << 9))] = r[j];
    __syncthreads();
    #pragma unroll
    for (int j = 0; j < 4; ++j)
        r[j] = X0[padl(t | ((unsigned)j << 9))];
    apply_gates(r, Gl, 17, 0, 2);          // gates c17,c18 = l9,l10 = j bits
}

// ---------------------------------------------------------------------------
// Single cooperative kernel, 6 layers x (pass A + pass B), 12 grid.syncs.
// Per-block prep: GCN fp64 -> feats[19]; gate matrices G[6][19][4] (LDS);
// feature-map phase tables W0[1024] (c bits 0..9, incl. -S/2) and W1[512]
// (bits 10..18, incl. 2^-9.5 amplitude) -- round-5-verified construction.
// A_0 synthesizes the FM product state at pinv(c) (ring applied by gather),
// then applies layer-0 gates: correct order FM -> ring -> gates_0.
// B_5 folds the final ring + <Z_0> into sign-twisted fp64 partials.
// Qubit q <-> bit k = 18-q. Fused gate U = RZ(t)*RX(t), c=cos(t/2), s=sin(t/2):
//   u00=(c^2,-sc) u01=(-s^2,-cs) u10=(s^2,-cs) u11=(c^2,sc)
// ---------------------------------------------------------------------------
__global__ __launch_bounds__(512, 1)
void k_all(Params P)
{
    __shared__ double sh_feats[NQ];
    __shared__ double sh_S;
    __shared__ float2 sh_G[6 * NQ * 4];          // gate matrices, layers 0..5
    __shared__ float2 W0[1024];                  // FM phases, c bits 0..9
    __shared__ float2 W1[512];                   // FM phases, bits 10..18 (+amp)
    __shared__ __align__(16) float2 stage[5120];
    __shared__ __align__(16) float2 X0[2560];
    __shared__ __align__(16) float2 X1[2560];
    __shared__ double sm[512];

    const unsigned t = threadIdx.x;
    const unsigned blk = blockIdx.x;
    cg::grid_group grid = cg::this_grid();

    // ---- per-block prep ----
    if (t == 0) {
        double deg[8], dis[8], h[8], o1[8], he[8], o2[8];
        for (int v = 0; v < 8; ++v) deg[v] = 1.0;                 // self loops
        for (int e = 0; e < 8; ++e) deg[P.ei[8 + e]] += 1.0;
        for (int v = 0; v < 8; ++v) dis[v] = 1.0 / sqrt(deg[v]);
        for (int v = 0; v < 8; ++v) {
            double s = 0.0;
            for (int k = 0; k < 4; ++k)
                s += (double)P.state[v * 4 + k] * (double)P.gnw[k];
            h[v] = s;
        }
        for (int v = 0; v < 8; ++v) o1[v] = h[v] * dis[v] * dis[v] + (double)P.gnb[0];
        for (int e = 0; e < 8; ++e) {
            int s = P.ei[e], d = P.ei[8 + e];
            o1[d] += h[s] * dis[s] * dis[d];
        }
        for (int j = 0; j < 9; ++j) {
            double a = (double)P.nb[j];
            for (int v = 0; v < 8; ++v) a += o1[v] * (double)P.nw[v * 9 + j];
            sh_feats[j] = a;
        }
        for (int e = 0; e < 8; ++e)
            he[e] = (double)P.mass[e] * (double)P.gew[0]
                  + (double)P.spin[e] * (double)P.gew[1]
                  + (double)P.charge[e] * (double)P.gew[2];
        for (int v = 0; v < 8; ++v) o2[v] = he[v] * dis[v] * dis[v] + (double)P.geb[0];
        for (int e = 0; e < 8; ++e) {
            int s = P.ei[e], d = P.ei[8 + e];
            o2[d] += he[s] * dis[s] * dis[d];
        }
        for (int j = 0; j < 8; ++j) {
            double a = (double)P.eb[j];
            for (int v = 0; v < 8; ++v) a += o2[v] * (double)P.ew[v * 8 + j];
            sh_feats[9 + j] = a;
        }
        sh_feats[17] = (double)P.p_norm[0];
        sh_feats[18] = (double)P.theta[0];
        double S = 0.0;
        for (int q = 0; q < NQ; ++q) S += sh_feats[q];
        sh_S = S;
    }
    __syncthreads();

    // gate matrices, layers 0..5 (layer l angle = qw[i,q,j], i=l/3, j=l%3)
    for (unsigned g = t; g < 6u * NQ; g += 512u) {
        int l = (int)(g / NQ), q = (int)(g % NQ);
        int i = l / 3, j = l % 3;
        double th = (double)P.qw[i * (NQ * 3) + q * 3 + j];
        double c = cos(0.5 * th), s = sin(0.5 * th);
        int k = 18 - q;
        float2* Ug = &sh_G[(l * NQ + k) * 4];
        Ug[0] = make_float2((float)(c * c), (float)(-s * c));
        Ug[1] = make_float2((float)(-s * s), (float)(-c * s));
        Ug[2] = make_float2((float)(s * s), (float)(-c * s));
        Ug[3] = make_float2((float)(c * c), (float)(s * c));
    }
    __syncthreads();

    // FM phase tables (round-5 construction): phi(b) = sum_k feats[18-k]*b_k - S/2
    {
        double S = sh_S;
        for (unsigned m = t; m < 1024u; m += 512u) {
            double a = -0.5 * S;
            for (int k = 0; k < 10; ++k)
                if ((m >> k) & 1u) a += sh_feats[18 - k];
            double sp, cp;
            sincos(a, &sp, &cp);
            W0[m] = make_float2((float)cp, (float)sp);
        }
        const double amp = 1.0 / sqrt((double)SZ);
        for (unsigned m = t; m < 512u; m += 512u) {
            double a = 0.0;
            for (int k = 0; k < 9; ++k)
                if ((m >> k) & 1u) a += sh_feats[8 - k];   // bit 10+k -> feats[18-(10+k)]
            double sp, cp;
            sincos(a, &sp, &cp);
            W1[m] = make_float2((float)(amp * cp), (float)(amp * sp));
        }
    }
    __syncthreads();

    const unsigned base = blk << 11;

    #pragma unroll 1
    for (int l = 0; l <= 5; ++l) {
        const float2* Gl = &sh_G[l * NQ * 4];
        float2* obuf = (l & 1) ? P.buf1 : P.buf0;
        const float2* ibuf = (l & 1) ? P.buf0 : P.buf1;
        float2 r[4];

        // ---- Pass A_l: ring-gather + gates c0..c10; block = c11..c18 ----
        if (l == 0) {
            // FM product state evaluated at pinv(c): FM -> ring -> gates_0
            #pragma unroll
            for (int j = 0; j < 4; ++j) {
                unsigned li = (t << 2) | (unsigned)j;
                unsigned b = pinv(base | li);
                float2 e0 = W0[b & 1023u];
                float2 e1 = W1[b >> 10];
                r[j] = make_float2(e0.x * e1.x - e0.y * e1.y,
                                   e0.x * e1.y + e0.y * e1.x);
            }
        } else {
            // 2 contiguous 2048-amp source regions (one per c0)
            const unsigned R0 = pinv(base) & ~2047u;
            const unsigned R1 = pinv(base | 1u) & ~2047u;
            #pragma unroll
            for (int k = 0; k < 4; ++k) {
                unsigned i = ((unsigned)k << 10) | (t << 1);
                unsigned g = (i < 2048u) ? (R0 + i) : (R1 + (i - 2048u));
                *reinterpret_cast<float4*>(&stage[padl(i)]) =
                    *reinterpret_cast<const float4*>(&ibuf[g]);
            }
            __syncthreads();
            #pragma unroll
            for (int j = 0; j < 4; ++j) {
                unsigned li = (t << 2) | (unsigned)j;
                unsigned b = pinv(base | li);
                r[j] = stage[padl(((li & 1u) << 11) | (b & 2047u))];
            }
        }
        passA_tail(r, Gl, t, X0, X1);
        #pragma unroll
        for (int j = 0; j < 4; ++j)
            obuf[base | t | ((unsigned)j << 9)] = r[j];
        __threadfence();
        grid.sync();

        // ---- Pass B_l: gates c11..c18 in place; block = c bits 3..10 ----
        #pragma unroll
        for (int j = 0; j < 4; ++j) {
            unsigned li = (t & 7u) | ((unsigned)j << 3) | ((t >> 3) << 5);
            unsigned c = (li & 7u) | (blk << 3) | ((li >> 3) << 11);
            r[j] = obuf[c];
        }
        passB_gates(r, Gl, t, X0, X1);

        if (l == 5) {
            // fold final ring + <Z_0>: sum (-1)^{popc(c & 0x3FFFF)} |psi|^2
            double acc = 0.0;
            #pragma unroll
            for (int j = 0; j < 4; ++j) {
                unsigned li = t | ((unsigned)j << 9);
                unsigned c = (li & 7u) | (blk << 3) | ((li >> 3) << 11);
                float2 v = r[j];
                double w = (double)v.x * v.x + (double)v.y * v.y;
                acc += (__popc(c & 0x3FFFFu) & 1) ? -w : w;
            }
            sm[t] = acc;
            __syncthreads();
            for (int st = 256; st > 0; st >>= 1) {
                if ((int)t < st) sm[t] += sm[t + st];
                __syncthreads();
            }
            if (t == 0) P.partial[blk] = sm[0];
        } else {
            #pragma unroll
            for (int j = 0; j < 4; ++j) {
                unsigned li = t | ((unsigned)j << 9);
                unsigned c = (li & 7u) | (blk << 3) | ((li >> 3) << 11);
                obuf[c] = r[j];
            }
        }
        __threadfence();
        grid.sync();
    }

    // ---- final: block 0 sums 256 partials ----
    if (blk == 0) {
        sm[t] = (t < 256u) ? P.partial[t] : 0.0;
        __syncthreads();
        for (int st = 256; st > 0; st >>= 1) {
            if ((int)t < st) sm[t] += sm[t + st];
            __syncthreads();
        }
        if (t == 0) P.out[0] = (float)sm[0];
    }
}

extern "C" void kernel_launch(void* const* d_in, const int* in_sizes, int n_in,
                              void* d_out, int out_size, void* d_ws, size_t ws_size,
                              hipStream_t stream)
{
    char* ws = (char*)d_ws;
    Params P;
    P.ei      = (const int*)d_in[0];
    P.state   = (const float*)d_in[1];
    P.mass    = (const float*)d_in[2];
    P.spin    = (const float*)d_in[3];
    P.charge  = (const float*)d_in[4];
    P.p_norm  = (const float*)d_in[5];
    P.theta   = (const float*)d_in[6];
    // d_in[7] = scattering (unused by reference)
    P.gnw     = (const float*)d_in[8];
    P.gnb     = (const float*)d_in[9];
    P.gew     = (const float*)d_in[10];
    P.geb     = (const float*)d_in[11];
    P.nw      = (const float*)d_in[12];
    P.nb      = (const float*)d_in[13];
    P.ew      = (const float*)d_in[14];
    P.eb      = (const float*)d_in[15];
    P.qw      = (const float*)d_in[16];
    P.partial = (double*)(ws);                  // 2 KiB
    P.buf0    = (float2*)(ws + 32768);          // 4 MiB
    P.buf1    = P.buf0 + SZ;                    // 4 MiB
    P.out     = (float*)d_out;

    void* args[] = { &P };
    hipLaunchCooperativeKernel(k_all, dim3(256), dim3(512), args, 0, stream);
}

// Round 8
// 104.104 us; speedup vs baseline: 11.0793x; 11.0793x over previous
//
#include <hip/hip_runtime.h>

#define NQ 19
#define SZ (1u << 19)

struct Params {
    const int* ei;
    const float* state; const float* mass; const float* spin; const float* charge;
    const float* p_norm; const float* theta;
    const float* gnw; const float* gnb; const float* gew; const float* geb;
    const float* nw; const float* nb; const float* ew; const float* eb;
    const float* qw;
    float2* buf0;
    unsigned* counter;
};

// Ring permutation inverse (bit space):
//   b = (c ^ (c>>1)) & 0x1FFFF ; b17 = c0^c17^c18 ; b18 = c0^c18
// Bits >=11 of pinv(c) depend ONLY on c0 and c bits 11..18.
__device__ __forceinline__ unsigned pinv(unsigned c)
{
    unsigned y = (c ^ (c >> 1)) & 0x1FFFFu;
    unsigned c0 = c & 1u, c17 = (c >> 17) & 1u, c18 = (c >> 18) & 1u;
    return y | ((c0 ^ c17 ^ c18) << 17) | ((c0 ^ c18) << 18);
}

// Padded LDS index: +2 float2 per 8 (keeps 8-groups intact; float4-safe).
__device__ __forceinline__ unsigned padl(unsigned l) { return l + 2u * (l >> 3); }

__device__ __forceinline__ void bfly(float2& a, float2& b,
                                     float2 u00, float2 u01,
                                     float2 u10, float2 u11)
{
    float2 na, nb;
    na.x = u00.x * a.x - u00.y * a.y + u01.x * b.x - u01.y * b.y;
    na.y = u00.x * a.y + u00.y * a.x + u01.x * b.y + u01.y * b.x;
    nb.x = u10.x * a.x - u10.y * a.y + u11.x * b.x - u11.y * b.y;
    nb.y = u10.x * a.y + u10.y * a.x + u11.x * b.y + u11.y * b.x;
    a = na;
    b = nb;
}

__device__ __forceinline__ void apply_gates(float2 r[4], const float2* Gl,
                                            int ampbit0, int jbit0, int n)
{
    #pragma unroll
    for (int k = 0; k < n; ++k) {
        const float2 u00 = Gl[(ampbit0 + k) * 4 + 0];
        const float2 u01 = Gl[(ampbit0 + k) * 4 + 1];
        const float2 u10 = Gl[(ampbit0 + k) * 4 + 2];
        const float2 u11 = Gl[(ampbit0 + k) * 4 + 3];
        const int m = 1 << (jbit0 + k);
        #pragma unroll
        for (int j = 0; j < 4; ++j)
            if (!(j & m)) bfly(r[j], r[j | m], u00, u01, u10, u11);
    }
}

// Build this layer's 19 gate matrices into LDS (one sincos per thread).
// Qubit q <-> bit k = 18-q. Fused gate U = RZ(t)*RX(t), c=cos(t/2), s=sin(t/2):
//   u00=(c^2,-sc) u01=(-s^2,-cs) u10=(s^2,-cs) u11=(c^2,sc)
__device__ __forceinline__ void build_G(float2* shG, const float* qw, int layer,
                                        unsigned t)
{
    if (t < NQ) {
        int k = (int)t, q = 18 - k;
        double th = (double)qw[(layer / 3) * (NQ * 3) + q * 3 + (layer % 3)];
        double c = cos(0.5 * th), s = sin(0.5 * th);
        shG[k * 4 + 0] = make_float2((float)(c * c), (float)(-s * c));
        shG[k * 4 + 1] = make_float2((float)(-s * s), (float)(-c * s));
        shG[k * 4 + 2] = make_float2((float)(s * s), (float)(-c * s));
        shG[k * 4 + 3] = make_float2((float)(c * c), (float)(s * c));
    }
}

// Pass-A tail: gates on c bits 0..10 through the 6 register layouts
// (round-5-verified index math). X1 may alias the (dead) staging buffer.
__device__ __forceinline__ void passA_tail(float2 r[4], const float2* Gl,
                                           unsigned t, float2* X0, float2* X1)
{
    apply_gates(r, Gl, 0, 0, 2);
    *reinterpret_cast<float4*>(&X0[padl(t << 2)]) =
        make_float4(r[0].x, r[0].y, r[1].x, r[1].y);
    *reinterpret_cast<float4*>(&X0[padl((t << 2) + 2u)]) =
        make_float4(r[2].x, r[2].y, r[3].x, r[3].y);
    __syncthreads();
    #pragma unroll
    for (int j = 0; j < 4; ++j)
        r[j] = X0[padl((t & 3u) | ((unsigned)j << 2) | ((t >> 2) << 4))];
    apply_gates(r, Gl, 2, 0, 2);
    #pragma unroll
    for (int j = 0; j < 4; ++j)
        X1[padl((t & 3u) | ((unsigned)j << 2) | ((t >> 2) << 4))] = r[j];
    __syncthreads();
    #pragma unroll
    for (int j = 0; j < 4; ++j)
        r[j] = X1[padl((t & 15u) | ((unsigned)j << 4) | ((t >> 4) << 6))];
    apply_gates(r, Gl, 4, 0, 2);
    #pragma unroll
    for (int j = 0; j < 4; ++j)
        X0[padl((t & 15u) | ((unsigned)j << 4) | ((t >> 4) << 6))] = r[j];
    __syncthreads();
    #pragma unroll
    for (int j = 0; j < 4; ++j)
        r[j] = X0[padl((t & 63u) | ((unsigned)j << 6) | ((t >> 6) << 8))];
    apply_gates(r, Gl, 6, 0, 2);
    #pragma unroll
    for (int j = 0; j < 4; ++j)
        X1[padl((t & 63u) | ((unsigned)j << 6) | ((t >> 6) << 8))] = r[j];
    __syncthreads();
    #pragma unroll
    for (int j = 0; j < 4; ++j)
        r[j] = X1[padl((t & 255u) | ((unsigned)j << 8) | ((t >> 8) << 10))];
    apply_gates(r, Gl, 8, 0, 2);
    #pragma unroll
    for (int j = 0; j < 4; ++j)
        X0[padl((t & 255u) | ((unsigned)j << 8) | ((t >> 8) << 10))] = r[j];
    __syncthreads();
    #pragma unroll
    for (int j = 0; j < 4; ++j)
        r[j] = X0[padl(t | ((unsigned)j << 9))];
    apply_gates(r, Gl, 10, 1, 1);          // gate c10 = l10 = j bit1
}

// Pass-B gates on c bits 11..18 (tile l: l0..l2=c0..c2, l3..l10=c11..c18).
__device__ __forceinline__ void passB_gates(float2 r[4], const float2* Gl,
                                            unsigned t, float2* X0, float2* X1)
{
    apply_gates(r, Gl, 11, 0, 2);
    #pragma unroll
    for (int j = 0; j < 4; ++j)
        X0[padl((t & 7u) | ((unsigned)j << 3) | ((t >> 3) << 5))] = r[j];
    __syncthreads();
    #pragma unroll
    for (int j = 0; j < 4; ++j)
        r[j] = X0[padl((t & 31u) | ((unsigned)j << 5) | ((t >> 5) << 7))];
    apply_gates(r, Gl, 13, 0, 2);
    #pragma unroll
    for (int j = 0; j < 4; ++j)
        X1[padl((t & 31u) | ((unsigned)j << 5) | ((t >> 5) << 7))] = r[j];
    __syncthreads();
    #pragma unroll
    for (int j = 0; j < 4; ++j)
        r[j] = X1[padl((t & 127u) | ((unsigned)j << 7) | ((t >> 7) << 9))];
    apply_gates(r, Gl, 15, 0, 2);
    #pragma unroll
    for (int j = 0; j < 4; ++j)
        X0[padl((t & 127u) | ((unsigned)j << 7) | ((t >> 7) << 9))] = r[j];
    __syncthreads();
    #pragma unroll
    for (int j = 0; j < 4; ++j)
        r[j] = X0[padl(t | ((unsigned)j << 9))];
    apply_gates(r, Gl, 17, 0, 2);          // gates c17,c18 = l9,l10 = j bits
}

// ---------------------------------------------------------------------------
// k_A0: fused prep + layer-0 pass A. Per-block: GCN fp64 -> feats (t0 serial),
// layer-0 G, FM phase tables W0[1024]/W1[512] (in `stage`), then synthesize
// the post-ring FM state (FM -> ring -> gates_0) and apply gates c0..c10.
// Block 0 resets the done-counter used by k_B(l=5).
// ---------------------------------------------------------------------------
__global__ __launch_bounds__(512, 4)
void k_A0(Params P)
{
    __shared__ __align__(16) float2 stage[5120];   // W0[0..1024) W1[1024..1536); X1 alias
    __shared__ __align__(16) float2 X0[2560];
    __shared__ float2 shG[NQ * 4];
    __shared__ double sh_feats[NQ];
    __shared__ double sh_S;

    const unsigned t = threadIdx.x;
    const unsigned blk = blockIdx.x;
    const unsigned base = blk << 11;

    if (blk == 0 && t == 0) *P.counter = 0u;       // reset for k_B(l=5)

    if (t == 0) {
        double deg[8], dis[8], h[8], o1[8], he[8], o2[8];
        for (int v = 0; v < 8; ++v) deg[v] = 1.0;                 // self loops
        for (int e = 0; e < 8; ++e) deg[P.ei[8 + e]] += 1.0;
        for (int v = 0; v < 8; ++v) dis[v] = 1.0 / sqrt(deg[v]);
        for (int v = 0; v < 8; ++v) {
            double s = 0.0;
            for (int k = 0; k < 4; ++k)
                s += (double)P.state[v * 4 + k] * (double)P.gnw[k];
            h[v] = s;
        }
        for (int v = 0; v < 8; ++v) o1[v] = h[v] * dis[v] * dis[v] + (double)P.gnb[0];
        for (int e = 0; e < 8; ++e) {
            int s = P.ei[e], d = P.ei[8 + e];
            o1[d] += h[s] * dis[s] * dis[d];
        }
        for (int j = 0; j < 9; ++j) {
            double a = (double)P.nb[j];
            for (int v = 0; v < 8; ++v) a += o1[v] * (double)P.nw[v * 9 + j];
            sh_feats[j] = a;
        }
        for (int e = 0; e < 8; ++e)
            he[e] = (double)P.mass[e] * (double)P.gew[0]
                  + (double)P.spin[e] * (double)P.gew[1]
                  + (double)P.charge[e] * (double)P.gew[2];
        for (int v = 0; v < 8; ++v) o2[v] = he[v] * dis[v] * dis[v] + (double)P.geb[0];
        for (int e = 0; e < 8; ++e) {
            int s = P.ei[e], d = P.ei[8 + e];
            o2[d] += he[s] * dis[s] * dis[d];
        }
        for (int j = 0; j < 8; ++j) {
            double a = (double)P.eb[j];
            for (int v = 0; v < 8; ++v) a += o2[v] * (double)P.ew[v * 8 + j];
            sh_feats[9 + j] = a;
        }
        sh_feats[17] = (double)P.p_norm[0];
        sh_feats[18] = (double)P.theta[0];
        double S = 0.0;
        for (int q = 0; q < NQ; ++q) S += sh_feats[q];
        sh_S = S;
    }
    __syncthreads();

    build_G(shG, P.qw, 0, t);
    // FM phase tables: phi(b) = sum_k feats[18-k]*b_k - S/2; amp in W1
    {
        double S = sh_S;
        for (unsigned m = t; m < 1024u; m += 512u) {
            double a = -0.5 * S;
            for (int k = 0; k < 10; ++k)
                if ((m >> k) & 1u) a += sh_feats[18 - k];
            double sp, cp;
            sincos(a, &sp, &cp);
            stage[m] = make_float2((float)cp, (float)sp);
        }
        const double amp = 1.0 / sqrt((double)SZ);
        for (unsigned m = t; m < 512u; m += 512u) {
            double a = 0.0;
            for (int k = 0; k < 9; ++k)
                if ((m >> k) & 1u) a += sh_feats[8 - k];
            double sp, cp;
            sincos(a, &sp, &cp);
            stage[1024u + m] = make_float2((float)(amp * cp), (float)(amp * sp));
        }
    }
    __syncthreads();

    float2 r[4];
    #pragma unroll
    for (int j = 0; j < 4; ++j) {
        unsigned li = (t << 2) | (unsigned)j;
        unsigned b = pinv(base | li);
        float2 e0 = stage[b & 1023u];
        float2 e1 = stage[1024u + (b >> 10)];
        r[j] = make_float2(e0.x * e1.x - e0.y * e1.y,
                           e0.x * e1.y + e0.y * e1.x);
    }
    passA_tail(r, shG, t, X0, stage);
    #pragma unroll
    for (int j = 0; j < 4; ++j)
        P.buf0[base | t | ((unsigned)j << 9)] = r[j];
}

// ---------------------------------------------------------------------------
// k_A (layers 1..5): ring-gather (coalesced 2-region staging) + gates c0..c10.
// 256 blocks x 512 threads; block = c bits 11..18. LDS 61 KiB -> 2 blocks/CU.
// ---------------------------------------------------------------------------
__global__ __launch_bounds__(512, 4)
void k_A(const float2* __restrict__ in, float2* __restrict__ out,
         const float* __restrict__ qw, int layer)
{
    __shared__ __align__(16) float2 stage[5120];   // gather staging; X1 alias
    __shared__ __align__(16) float2 X0[2560];
    __shared__ float2 shG[NQ * 4];
    const unsigned t = threadIdx.x;
    const unsigned base = blockIdx.x << 11;

    build_G(shG, qw, layer, t);
    const unsigned R0 = pinv(base) & ~2047u;
    const unsigned R1 = pinv(base | 1u) & ~2047u;
    #pragma unroll
    for (int k = 0; k < 4; ++k) {
        unsigned i = ((unsigned)k << 10) | (t << 1);
        unsigned g = (i < 2048u) ? (R0 + i) : (R1 + (i - 2048u));
        *reinterpret_cast<float4*>(&stage[padl(i)]) =
            *reinterpret_cast<const float4*>(&in[g]);
    }
    __syncthreads();

    float2 r[4];
    #pragma unroll
    for (int j = 0; j < 4; ++j) {
        unsigned li = (t << 2) | (unsigned)j;
        unsigned b = pinv(base | li);
        r[j] = stage[padl(((li & 1u) << 11) | (b & 2047u))];
    }
    passA_tail(r, shG, t, X0, stage);
    #pragma unroll
    for (int j = 0; j < 4; ++j)
        out[base | t | ((unsigned)j << 9)] = r[j];
}

// ---------------------------------------------------------------------------
// k_B: gates c11..c18 in place; block = c bits 3..10 (64B contiguous runs).
// do_reduce (layer 5): fold final ring + <Z_0> into sign-twisted fp64
// partials; last-done block (atomic counter) sums partial[0..255] in order
// (deterministic) with AGENT-scope loads and writes out[0].
// ---------------------------------------------------------------------------
__global__ __launch_bounds__(512, 4)
void k_B(float2* __restrict__ buf, const float* __restrict__ qw, int layer,
         int do_reduce, double* __restrict__ partial,
         unsigned* __restrict__ counter, float* __restrict__ out)
{
    __shared__ __align__(16) float2 X0[2560];
    __shared__ __align__(16) float2 X1[2560];
    __shared__ double sm[512];
    __shared__ float2 shG[NQ * 4];
    __shared__ int who;
    const unsigned t = threadIdx.x;
    const unsigned blk = blockIdx.x;

    build_G(shG, qw, layer, t);
    float2 r[4];
    #pragma unroll
    for (int j = 0; j < 4; ++j) {
        unsigned li = (t & 7u) | ((unsigned)j << 3) | ((t >> 3) << 5);
        unsigned c = (li & 7u) | (blk << 3) | ((li >> 3) << 11);
        r[j] = buf[c];
    }
    __syncthreads();
    passB_gates(r, shG, t, X0, X1);

    if (do_reduce) {
        double acc = 0.0;
        #pragma unroll
        for (int j = 0; j < 4; ++j) {
            unsigned li = t | ((unsigned)j << 9);
            unsigned c = (li & 7u) | (blk << 3) | ((li >> 3) << 11);
            float2 v = r[j];
            double w = (double)v.x * v.x + (double)v.y * v.y;
            acc += (__popc(c & 0x3FFFFu) & 1) ? -w : w;
        }
        sm[t] = acc;
        __syncthreads();
        for (int st = 256; st > 0; st >>= 1) {
            if ((int)t < st) sm[t] += sm[t + st];
            __syncthreads();
        }
        if (t == 0) {
            partial[blk] = sm[0];
            __threadfence();
            unsigned old = atomicAdd(counter, 1u);
            who = (old == 255u);
        }
        __syncthreads();
        if (who) {
            double v = (t < 256u)
                ? __hip_atomic_load(&partial[t], __ATOMIC_RELAXED,
                                    __HIP_MEMORY_SCOPE_AGENT)
                : 0.0;
            sm[t] = v;
            __syncthreads();
            for (int st = 256; st > 0; st >>= 1) {
                if ((int)t < st) sm[t] += sm[t + st];
                __syncthreads();
            }
            if (t == 0) out[0] = (float)sm[0];
        }
    } else {
        #pragma unroll
        for (int j = 0; j < 4; ++j) {
            unsigned li = t | ((unsigned)j << 9);
            unsigned c = (li & 7u) | (blk << 3) | ((li >> 3) << 11);
            buf[c] = r[j];
        }
    }
}

extern "C" void kernel_launch(void* const* d_in, const int* in_sizes, int n_in,
                              void* d_out, int out_size, void* d_ws, size_t ws_size,
                              hipStream_t stream)
{
    char* ws = (char*)d_ws;
    double*   partial = (double*)(ws + 16384);        // 2 KiB
    unsigned* counter = (unsigned*)(ws + 20480);
    float2*   buf0    = (float2*)(ws + 32768);        // 4 MiB
    float2*   buf1    = buf0 + SZ;                    // 4 MiB
    const float* qw   = (const float*)d_in[16];
    float* out        = (float*)d_out;

    Params P;
    P.ei      = (const int*)d_in[0];
    P.state   = (const float*)d_in[1];
    P.mass    = (const float*)d_in[2];
    P.spin    = (const float*)d_in[3];
    P.charge  = (const float*)d_in[4];
    P.p_norm  = (const float*)d_in[5];
    P.theta   = (const float*)d_in[6];
    // d_in[7] = scattering (unused by reference)
    P.gnw     = (const float*)d_in[8];
    P.gnb     = (const float*)d_in[9];
    P.gew     = (const float*)d_in[10];
    P.geb     = (const float*)d_in[11];
    P.nw      = (const float*)d_in[12];
    P.nb      = (const float*)d_in[13];
    P.ew      = (const float*)d_in[14];
    P.eb      = (const float*)d_in[15];
    P.qw      = qw;
    P.buf0    = buf0;
    P.counter = counter;

    k_A0<<<256, 512, 0, stream>>>(P);
    k_B<<<256, 512, 0, stream>>>(buf0, qw, 0, 0, partial, counter, out);
    for (int l = 1; l <= 5; ++l) {
        float2* in  = (l & 1) ? buf0 : buf1;
        float2* o   = (l & 1) ? buf1 : buf0;
        k_A<<<256, 512, 0, stream>>>(in, o, qw, l);
        k_B<<<256, 512, 0, stream>>>(o, qw, l, l == 5, partial, counter, out);
    }
}